// Round 1
// baseline (892.240 us; speedup 1.0000x reference)
//
#include <hip/hip_runtime.h>
#include <math.h>

#define VOCAB   5000
#define T_CTC   512
#define S_TGT   128
#define BATCH   16
#define L_EXT   257            // 2*S+1
#define NEGV    (-1e30f)
#define ALPHA_W 0.2f
#define CONF    0.9f           // 1 - smoothing
#define OFFV    (0.1f / 4999.0f)

__device__ __forceinline__ float lae(float a, float b) {
    float mx = fmaxf(a, b);
    float d  = fminf(a, b) - mx;          // <= 0, finite
    return mx + log1pf(__expf(d));
}

__global__ __launch_bounds__(320)
void fused_loss_kernel(const float* __restrict__ att,   // (16,128,5000)
                       const float* __restrict__ ctc,   // (16,512,5000)
                       const int*   __restrict__ tgt,   // (16,128)
                       float*       __restrict__ ws)    // ws[0]=att_sum ws[1]=ctc_sum
{
    if (blockIdx.x < BATCH) {
        // ---------------- CTC forward recursion, one block per batch ----------------
        const int b = blockIdx.x;
        const int s = threadIdx.x;                 // extended-state index
        __shared__ float alpha[L_EXT + 3];
        __shared__ int   tg[S_TGT];

        if (threadIdx.x < S_TGT) tg[threadIdx.x] = tgt[b * S_TGT + threadIdx.x];
        __syncthreads();

        const bool active = (s < L_EXT);
        int  ext    = 0;       // blank
        bool allow2 = false;
        if (active && (s & 1)) {
            ext = tg[(s - 1) >> 1];
            if (s >= 3) allow2 = (ext != 0) && (ext != tg[(s - 3) >> 1]);
        }
        const float* rowbase = ctc + (size_t)b * T_CTC * VOCAB + ext;

        // alpha0: emit[0] for s<2, else NEG
        if (active) alpha[s] = (s < 2) ? rowbase[0] : NEGV;
        __syncthreads();

        // depth-4 emit prefetch ring
        float ebuf[4];
        #pragma unroll
        for (int i = 0; i < 4; ++i) {
            int t = 1 + i;
            ebuf[i] = (active && t < T_CTC) ? rowbase[(size_t)t * VOCAB] : 0.0f;
        }

        #pragma unroll 4
        for (int t = 1; t < T_CTC; ++t) {
            float e    = ebuf[(t - 1) & 3];
            int   tp   = t + 4;
            float enew = (active && tp < T_CTC) ? rowbase[(size_t)tp * VOCAB] : 0.0f;

            float a  = NEGV, a1 = NEGV, a2 = NEGV;
            if (active) {
                a  = alpha[s];
                a1 = (s >= 1) ? alpha[s - 1] : NEGV;
                a2 = allow2   ? alpha[s - 2] : NEGV;
            }
            __syncthreads();                       // reads done before writes
            if (active) alpha[s] = lae(lae(a, a1), a2) + e;
            ebuf[(t - 1) & 3] = enew;
            __syncthreads();                       // writes done before next reads
        }

        if (threadIdx.x == 0) {
            float ll     = lae(alpha[L_EXT - 1], alpha[L_EXT - 2]);
            float loss_b = -ll;
            if (loss_b > 1e20f) loss_b = 0.0f;     // zero_infinity
            atomicAdd(&ws[1], loss_b);
        }
    } else {
        // ---------------- label-smoothing loss, one block per (b,s) row -------------
        const int r = blockIdx.x - BATCH;          // 0..2047
        const float* row = att + (size_t)r * VOCAB;
        const float4* row4 = (const float4*)row;   // 5000/4 = 1250 exact

        float sum = 0.0f;
        for (int i = threadIdx.x; i < VOCAB / 4; i += blockDim.x) {
            float4 v = row4[i];
            sum += v.x + v.y + v.z + v.w;
        }
        #pragma unroll
        for (int off = 32; off > 0; off >>= 1)
            sum += __shfl_down(sum, off, 64);

        __shared__ float wsum[5];
        const int wave = threadIdx.x >> 6;
        if ((threadIdx.x & 63) == 0) wsum[wave] = sum;
        __syncthreads();
        if (threadIdx.x == 0) {
            float rs = wsum[0] + wsum[1] + wsum[2] + wsum[3] + wsum[4];
            float tl = row[tgt[r]];
            float per_row = -(CONF * tl + OFFV * (rs - tl));
            atomicAdd(&ws[0], per_row);
        }
    }
}

__global__ void combine_kernel(const float* __restrict__ ws, float* __restrict__ out)
{
    if (threadIdx.x == 0 && blockIdx.x == 0) {
        // att: mean over 2048 rows; ctc: mean_b(loss_b / S) = sum / (16*128) = /2048
        const float inv = 1.0f / (float)(BATCH * S_TGT);
        float att_loss = ws[0] * inv;
        float ctc_loss = ws[1] * inv;
        out[0] = ALPHA_W * att_loss + (1.0f - ALPHA_W) * ctc_loss;
    }
}

extern "C" void kernel_launch(void* const* d_in, const int* in_sizes, int n_in,
                              void* d_out, int out_size, void* d_ws, size_t ws_size,
                              hipStream_t stream)
{
    const float* att = (const float*)d_in[0];
    const float* ctc = (const float*)d_in[1];
    const int*   tgt = (const int*)d_in[2];
    float* out = (float*)d_out;
    float* ws  = (float*)d_ws;

    hipMemsetAsync(ws, 0, 2 * sizeof(float), stream);
    // CTC blocks first (long-pole, 16 of them), then 2048 label-smoothing rows.
    fused_loss_kernel<<<BATCH + BATCH * S_TGT, 320, 0, stream>>>(att, ctc, tgt, ws);
    combine_kernel<<<1, 64, 0, stream>>>(ws, out);
}